// Round 1
// baseline (264.834 us; speedup 1.0000x reference)
//
#include <hip/hip_runtime.h>
#include <hip/hip_bf16.h>

// BlocDiagLinear: out[b, n*128+r] = sum_c x[b, n*128+c] * blocks[n, r, c]
// 64 independent GEMMs M=4096 N=128 K=128, fp32 I/O, bf16 MFMA compute.
// Memory-bound: ~272 MB HBM traffic -> ~43 us floor at 6.3 TB/s.

typedef __bf16 bf16_8 __attribute__((ext_vector_type(8)));
typedef __bf16 bf16_4 __attribute__((ext_vector_type(4)));
typedef float f32x4 __attribute__((ext_vector_type(4)));

#define LDS_K 136  // 128 + 8 pad: row stride 272 B -> 4-bank shift per row -> 2-way (free) conflicts

__global__ __launch_bounds__(256, 2)
void BlocDiagLinear_kernel(const float* __restrict__ x,
                           const float* __restrict__ blocks,
                           float* __restrict__ out)
{
    __shared__ __align__(16) __bf16 xs[128 * LDS_K];
    __shared__ __align__(16) __bf16 ws[128 * LDS_K];

    const int bid = blockIdx.x;
    const int nb  = bid >> 5;   // block index 0..63
    const int mt  = bid & 31;   // batch tile 0..31

    const int t  = threadIdx.x;   // 0..255
    const int c4 = t & 31;        // float4 column within 128-wide tile
    const int r0 = t >> 5;        // base row 0..7

    const float* xg = x + (size_t)mt * 128 * 8192 + (size_t)nb * 128;
    const float* wg = blocks + (size_t)nb * 16384;

    // Stage x tile (128x128) and W block (128x128) fp32 -> bf16 into LDS.
    // Each thread: 16 rows x 1 float4. Coalesced: 32 threads cover a 512B row segment.
#pragma unroll
    for (int i = 0; i < 16; ++i) {
        const int row = i * 8 + r0;
        const float4 vx = *(const float4*)(xg + (size_t)row * 8192 + c4 * 4);
        const float4 vw = *(const float4*)(wg + row * 128 + c4 * 4);
        bf16_4 bx = { (__bf16)vx.x, (__bf16)vx.y, (__bf16)vx.z, (__bf16)vx.w };
        bf16_4 bw = { (__bf16)vw.x, (__bf16)vw.y, (__bf16)vw.z, (__bf16)vw.w };
        *(bf16_4*)(xs + row * LDS_K + c4 * 4) = bx;
        *(bf16_4*)(ws + row * LDS_K + c4 * 4) = bw;
    }
    __syncthreads();

    // 4 waves in 2x2 grid; each wave computes a 64x64 sub-tile as 4x4 MFMA 16x16 frags.
    const int lane = t & 63;
    const int w    = t >> 6;
    const int wm   = w >> 1;
    const int wn   = w & 1;
    const int lm   = lane & 15;   // A: m index / B: n index
    const int q    = lane >> 4;   // k-group

    f32x4 acc[4][4];
#pragma unroll
    for (int mi = 0; mi < 4; ++mi)
#pragma unroll
        for (int ni = 0; ni < 4; ++ni)
            acc[mi][ni] = (f32x4){0.f, 0.f, 0.f, 0.f};

#pragma unroll
    for (int kk = 0; kk < 4; ++kk) {
        const int k0 = kk * 32 + q * 8;
        bf16_8 a[4], b[4];
#pragma unroll
        for (int mi = 0; mi < 4; ++mi)
            a[mi] = *(const bf16_8*)(xs + (wm * 64 + mi * 16 + lm) * LDS_K + k0);
#pragma unroll
        for (int ni = 0; ni < 4; ++ni)
            b[ni] = *(const bf16_8*)(ws + (wn * 64 + ni * 16 + lm) * LDS_K + k0);
#pragma unroll
        for (int mi = 0; mi < 4; ++mi)
#pragma unroll
            for (int ni = 0; ni < 4; ++ni)
                acc[mi][ni] = __builtin_amdgcn_mfma_f32_16x16x32_bf16(
                                  a[mi], b[ni], acc[mi][ni], 0, 0, 0);
    }

    // Epilogue: D layout col = lane&15 (r), row = q*4 + reg (batch).
    float* og = out + (size_t)(mt * 128 + wm * 64 + q * 4) * 8192
                    + (size_t)nb * 128 + wn * 64 + lm;
#pragma unroll
    for (int mi = 0; mi < 4; ++mi)
#pragma unroll
        for (int ni = 0; ni < 4; ++ni)
#pragma unroll
            for (int i = 0; i < 4; ++i)
                og[(size_t)(mi * 16 + i) * 8192 + ni * 16] = acc[mi][ni][i];
}

extern "C" void kernel_launch(void* const* d_in, const int* in_sizes, int n_in,
                              void* d_out, int out_size, void* d_ws, size_t ws_size,
                              hipStream_t stream) {
    const float* x      = (const float*)d_in[0];
    const float* blocks = (const float*)d_in[1];
    float* out          = (float*)d_out;
    BlocDiagLinear_kernel<<<dim3(64 * 32), dim3(256), 0, stream>>>(x, blocks, out);
}

// Round 2
// 263.351 us; speedup vs baseline: 1.0056x; 1.0056x over previous
//
#include <hip/hip_runtime.h>
#include <hip/hip_bf16.h>

// BlocDiagLinear: out[b, n*128+r] = sum_c x[b, n*128+c] * blocks[n, r, c]
// 64 independent GEMMs M=4096 N=128 K=128, fp32 I/O, bf16 MFMA compute.
// R2: x loaded direct-to-register (no reuse -> no LDS); only W staged in LDS.
// LDS 34.8 KB -> 4 WG/CU (16/32 waves) vs R1's 2 WG/CU at 68 KB.

typedef __bf16 bf16_8 __attribute__((ext_vector_type(8)));
typedef __bf16 bf16_4 __attribute__((ext_vector_type(4)));
typedef float f32x4 __attribute__((ext_vector_type(4)));

#define LDS_K 136  // 128 + 8 pad: row stride 272 B -> 4-bank shift/row -> 2-way (free) conflicts

__global__ __launch_bounds__(256, 4)
void BlocDiagLinear_kernel(const float* __restrict__ x,
                           const float* __restrict__ blocks,
                           float* __restrict__ out)
{
    __shared__ __align__(16) __bf16 ws[128 * LDS_K];  // 34816 B

    const int bid = blockIdx.x;
    const int nb  = bid >> 5;   // block index 0..63
    const int mt  = bid & 31;   // batch tile 0..31

    const int t  = threadIdx.x;   // 0..255
    const int c4 = t & 31;        // float4 column within 128-wide tile
    const int r0 = t >> 5;        // base row 0..7

    // Stage W block (128x128) fp32 -> bf16 into LDS. 16 rows x 1 float4 per thread.
    const float* wg = blocks + (size_t)nb * 16384;
#pragma unroll
    for (int i = 0; i < 16; ++i) {
        const int row = i * 8 + r0;
        const float4 vw = *(const float4*)(wg + row * 128 + c4 * 4);
        bf16_4 bw = { (__bf16)vw.x, (__bf16)vw.y, (__bf16)vw.z, (__bf16)vw.w };
        *(bf16_4*)(ws + row * LDS_K + c4 * 4) = bw;
    }
    __syncthreads();

    // 4 waves in 2x2 grid; each wave computes a 64x64 sub-tile as 4x4 MFMA 16x16 frags.
    const int lane = t & 63;
    const int w    = t >> 6;
    const int wm   = w >> 1;      // batch-halves
    const int wn   = w & 1;       // r-halves
    const int lm   = lane & 15;   // A: m index / B: n index
    const int q    = lane >> 4;   // k-group

    // Per-lane A base: row (mt*128 + wm*64 + lm), col nb*128 + q*8
    const float* xa = x + (size_t)(mt * 128 + wm * 64 + lm) * 8192
                        + (size_t)nb * 128 + q * 8;

    f32x4 acc[4][4];
#pragma unroll
    for (int mi = 0; mi < 4; ++mi)
#pragma unroll
        for (int ni = 0; ni < 4; ++ni)
            acc[mi][ni] = (f32x4){0.f, 0.f, 0.f, 0.f};

#pragma unroll
    for (int kk = 0; kk < 4; ++kk) {
        const int k0 = kk * 32 + q * 8;
        // A fragments: direct global load, 8 consecutive fp32 per lane -> bf16.
        bf16_8 a[4];
#pragma unroll
        for (int mi = 0; mi < 4; ++mi) {
            const float* p = xa + (size_t)mi * 16 * 8192 + kk * 32;
            const float4 lo = *(const float4*)(p);
            const float4 hi = *(const float4*)(p + 4);
            bf16_8 af = { (__bf16)lo.x, (__bf16)lo.y, (__bf16)lo.z, (__bf16)lo.w,
                          (__bf16)hi.x, (__bf16)hi.y, (__bf16)hi.z, (__bf16)hi.w };
            a[mi] = af;
        }
        bf16_8 b[4];
#pragma unroll
        for (int ni = 0; ni < 4; ++ni)
            b[ni] = *(const bf16_8*)(ws + (wn * 64 + ni * 16 + lm) * LDS_K + k0);
#pragma unroll
        for (int mi = 0; mi < 4; ++mi)
#pragma unroll
            for (int ni = 0; ni < 4; ++ni)
                acc[mi][ni] = __builtin_amdgcn_mfma_f32_16x16x32_bf16(
                                  a[mi], b[ni], acc[mi][ni], 0, 0, 0);
    }

    // Epilogue: D layout col = lane&15 (r), row = q*4 + reg (batch).
    float* og = out + (size_t)(mt * 128 + wm * 64 + q * 4) * 8192
                    + (size_t)nb * 128 + wn * 64 + lm;
#pragma unroll
    for (int mi = 0; mi < 4; ++mi)
#pragma unroll
        for (int ni = 0; ni < 4; ++ni)
#pragma unroll
            for (int i = 0; i < 4; ++i)
                og[(size_t)(mi * 16 + i) * 8192 + ni * 16] = acc[mi][ni][i];
}

extern "C" void kernel_launch(void* const* d_in, const int* in_sizes, int n_in,
                              void* d_out, int out_size, void* d_ws, size_t ws_size,
                              hipStream_t stream) {
    const float* x      = (const float*)d_in[0];
    const float* blocks = (const float*)d_in[1];
    float* out          = (float*)d_out;
    BlocDiagLinear_kernel<<<dim3(64 * 32), dim3(256), 0, stream>>>(x, blocks, out);
}

// Round 3
// 246.109 us; speedup vs baseline: 1.0761x; 1.0701x over previous
//
#include <hip/hip_runtime.h>
#include <hip/hip_bf16.h>

// BlocDiagLinear: out[b, n*128+r] = sum_c x[b, n*128+c] * blocks[n, r, c]
// 64 GEMMs M=4096 N=128 K=128, fp32 I/O, bf16 MFMA.
// R3: (1) nb = fast WG index -> resident WGs span all 64 column-granule
//     classes (channel balance); (2) A=W / B=x so D maps reg->r => float4
//     epilogue stores; (3) manual ni-pipeline: next x-gather overlaps MFMA.

typedef __bf16 bf16_8 __attribute__((ext_vector_type(8)));
typedef __bf16 bf16_4 __attribute__((ext_vector_type(4)));
typedef float f32x4 __attribute__((ext_vector_type(4)));

#define LDS_K 136  // 128+8 pad: 272 B row stride -> 2-way (free) bank aliasing

__global__ __launch_bounds__(256, 3)
void BlocDiagLinear_kernel(const float* __restrict__ x,
                           const float* __restrict__ blocks,
                           float* __restrict__ out)
{
    __shared__ __align__(16) __bf16 ws[128 * LDS_K];  // 34816 B

    const int bid = blockIdx.x;
    const int nb  = bid & 63;   // block index — FAST index across resident WGs
    const int mt  = bid >> 6;   // batch tile 0..31

    const int t  = threadIdx.x;
    const int c4 = t & 31;
    const int r0 = t >> 5;

    // Stage W block (128x128) fp32 -> bf16 into LDS (coalesced float4).
    const float* wg = blocks + (size_t)nb * 16384;
#pragma unroll
    for (int i = 0; i < 16; ++i) {
        const int row = i * 8 + r0;
        const float4 vw = *(const float4*)(wg + row * 128 + c4 * 4);
        bf16_4 bw = { (__bf16)vw.x, (__bf16)vw.y, (__bf16)vw.z, (__bf16)vw.w };
        *(bf16_4*)(ws + row * LDS_K + c4 * 4) = bw;
    }
    __syncthreads();

    const int lane = t & 63;
    const int w    = t >> 6;
    const int wm   = w >> 1;      // r-half (W rows)
    const int wn   = w & 1;       // batch-half
    const int lm   = lane & 15;
    const int q    = lane >> 4;

    // B-operand (x) per-lane base: batch row mt*128 + wn*64 + lm, col nb*128 + q*8
    const float* xb = x + (size_t)(mt * 128 + wn * 64 + lm) * 8192
                        + (size_t)nb * 128 + q * 8;

    f32x4 acc[4][4];
#pragma unroll
    for (int mi = 0; mi < 4; ++mi)
#pragma unroll
        for (int ni = 0; ni < 4; ++ni)
            acc[mi][ni] = (f32x4){0.f, 0.f, 0.f, 0.f};

    // Pipeline over ni (batch groups of 16 rows): load raw fp32 for ni, then
    // while converting/MFMAing, the loads for ni+1 are already in flight.
    float4 raw[8];
#pragma unroll
    for (int kk = 0; kk < 4; ++kk) {
        raw[2 * kk]     = *(const float4*)(xb + kk * 32);
        raw[2 * kk + 1] = *(const float4*)(xb + kk * 32 + 4);
    }

#pragma unroll
    for (int ni = 0; ni < 4; ++ni) {
        bf16_8 b[4];
#pragma unroll
        for (int kk = 0; kk < 4; ++kk) {
            const float4 lo = raw[2 * kk];
            const float4 hi = raw[2 * kk + 1];
            b[kk] = (bf16_8){ (__bf16)lo.x, (__bf16)lo.y, (__bf16)lo.z, (__bf16)lo.w,
                              (__bf16)hi.x, (__bf16)hi.y, (__bf16)hi.z, (__bf16)hi.w };
        }
        if (ni < 3) {
            const float* p = xb + (size_t)(ni + 1) * 16 * 8192;
#pragma unroll
            for (int kk = 0; kk < 4; ++kk) {
                raw[2 * kk]     = *(const float4*)(p + kk * 32);
                raw[2 * kk + 1] = *(const float4*)(p + kk * 32 + 4);
            }
        }
#pragma unroll
        for (int kk = 0; kk < 4; ++kk) {
            bf16_8 a[4];
#pragma unroll
            for (int mi = 0; mi < 4; ++mi)
                a[mi] = *(const bf16_8*)(ws + (wm * 64 + mi * 16 + lm) * LDS_K
                                            + kk * 32 + q * 8);
#pragma unroll
            for (int mi = 0; mi < 4; ++mi)
                acc[mi][ni] = __builtin_amdgcn_mfma_f32_16x16x32_bf16(
                                  a[mi], b[kk], acc[mi][ni], 0, 0, 0);
        }
    }

    // Epilogue: D row = q*4+reg -> r (consecutive!), col = lm -> batch row.
    // Each thread stores 16 float4 (contiguous 16 B along r).
    float* og = out + (size_t)(mt * 128 + wn * 64 + lm) * 8192
                    + (size_t)nb * 128 + wm * 64 + q * 4;
#pragma unroll
    for (int ni = 0; ni < 4; ++ni)
#pragma unroll
        for (int mi = 0; mi < 4; ++mi)
            *(f32x4*)(og + (size_t)ni * 16 * 8192 + mi * 16) = acc[mi][ni];
}

extern "C" void kernel_launch(void* const* d_in, const int* in_sizes, int n_in,
                              void* d_out, int out_size, void* d_ws, size_t ws_size,
                              hipStream_t stream) {
    const float* x      = (const float*)d_in[0];
    const float* blocks = (const float*)d_in[1];
    float* out          = (float*)d_out;
    BlocDiagLinear_kernel<<<dim3(64 * 32), dim3(256), 0, stream>>>(x, blocks, out);
}